// Round 1
// baseline (582.167 us; speedup 1.0000x reference)
//
#include <hip/hip_runtime.h>

// ---------- helpers ----------

__device__ inline unsigned short f2b(float f) {
    union { float f; unsigned u; } v; v.f = f;
    unsigned u = v.u;
    u += 0x7FFFu + ((u >> 16) & 1u);   // RNE
    return (unsigned short)(u >> 16);
}

__device__ inline void gload_lds16(const void* gptr, void* ldsptr) {
    __builtin_amdgcn_global_load_lds(
        (const __attribute__((address_space(1))) unsigned int*)gptr,
        (__attribute__((address_space(3))) unsigned int*)ldsptr,
        16, 0, 0);
}

typedef __attribute__((ext_vector_type(8))) short  bf16x8;   // 8 bf16 in 4 VGPRs
typedef __attribute__((ext_vector_type(4))) float  f32x4;

// ---------- kernel 1: dequant qweight -> Wt [N][K] bf16 ----------
// grid (K/64, N/64), block 256. Tile transposed through LDS (fp32, pad 65).
__global__ __launch_bounds__(256) void dequant_wt(
    const int* __restrict__ qw, const int* __restrict__ qz,
    const float* __restrict__ sc, unsigned short* __restrict__ Wt,
    int K, int N, int gs)
{
    __shared__ float tile[64 * 65];   // [n_local][k_local], pad 65 (2-way max conflict)
    const int k0 = blockIdx.x * 64, n0 = blockIdx.y * 64;
    const int g  = k0 / gs;           // 64 | gs -> uniform per block
    const int np8 = N >> 3;
    const int tid = threadIdx.x;

#pragma unroll
    for (int i = 0; i < 2; i++) {
        int e  = i * 256 + tid;       // 0..511
        int kk = e >> 3, pp = e & 7;
        int w = qw[(size_t)(k0 + kk) * np8 + (n0 >> 3) + pp];
        int z = qz[(size_t)g * np8 + (n0 >> 3) + pp];
        const float* s = sc + (size_t)g * N + n0 + pp * 8;
#pragma unroll
        for (int j = 0; j < 8; j++) {
            int q  = (w >> (4 * j)) & 15;
            int zz = (z >> (4 * j)) & 15;
            tile[(pp * 8 + j) * 65 + kk] = (float)(q - zz) * s[j];
        }
    }
    __syncthreads();
#pragma unroll
    for (int i = 0; i < 2; i++) {
        int e   = i * 256 + tid;
        int nn  = e >> 3, kk0 = (e & 7) * 8;
        __align__(16) unsigned short o[8];
#pragma unroll
        for (int j = 0; j < 8; j++) o[j] = f2b(tile[nn * 65 + kk0 + j]);
        *(uint4*)(Wt + (size_t)(n0 + nn) * K + k0 + kk0) = *(const uint4*)o;
    }
}

// ---------- kernel 2: x fp32 -> bf16 ----------
__global__ __launch_bounds__(256) void convert_x(
    const float* __restrict__ x, unsigned short* __restrict__ xb, size_t n)
{
    size_t i = ((size_t)blockIdx.x * 256 + threadIdx.x) * 8;
    if (i >= n) return;
    float4 v0 = *(const float4*)(x + i);
    float4 v1 = *(const float4*)(x + i + 4);
    __align__(16) unsigned short o[8] = {
        f2b(v0.x), f2b(v0.y), f2b(v0.z), f2b(v0.w),
        f2b(v1.x), f2b(v1.y), f2b(v1.z), f2b(v1.w)};
    *(uint4*)(xb + i) = *(const uint4*)o;
}

// ---------- kernel 3: bf16 MFMA GEMM, m97 structure ----------
// A [M,K] (bf16 or fp32 per template), Bt [N,K] bf16, C [M,N] fp32 (+bias).
// 128x128 tile, BK=32, 256 thr = 4 waves in 2x2, each wave 64x64 via 4x4
// mfma_f32_16x16x32_bf16. Staging via global_load_lds width 16.
template <bool A_F32>
__global__ __launch_bounds__(256) void gemm_bt(
    const void* __restrict__ Aptr, const unsigned short* __restrict__ Bt,
    const float* __restrict__ bias, float* __restrict__ C,
    int M, int N, int K)
{
    constexpr int BM = 128, BN = 128, BK = 32;
    __shared__ unsigned short As[BM * BK];  // [m][k] 8 KB
    __shared__ unsigned short Bs[BN * BK];  // [n][k] 8 KB

    const int tid  = threadIdx.x;
    const int wave = tid >> 6, lane = tid & 63;
    const int quad = lane >> 4, l16 = lane & 15;
    const int n0 = blockIdx.x * BN;         // n fastest -> A L3-resident
    const int m0 = blockIdx.y * BM;
    const int wm = (wave >> 1) * 64, wn = (wave & 1) * 64;

    f32x4 acc[4][4] = {};

    for (int kt = 0; kt < K; kt += BK) {
        __syncthreads();   // previous compute done before LDS overwrite
        // stage B tile (128 rows x 32 bf16 = 64B/row, 4 lanes/row)
#pragma unroll
        for (int i = 0; i < 2; i++) {
            int e = i * 256 + tid;          // 0..511 16B-chunks
            int row = e >> 2, seg = e & 3;
            gload_lds16(Bt + (size_t)(n0 + row) * K + kt + seg * 8,
                        (char*)Bs + e * 16);
        }
        // stage A tile
        if (A_F32) {
            const float* Af = (const float*)Aptr;
#pragma unroll
            for (int i = 0; i < 4; i++) {
                int e = i * 256 + tid;      // 0..1023 float4-chunks
                int row = e >> 3, seg = e & 7;
                float4 v = *(const float4*)(Af + (size_t)(m0 + row) * K + kt + seg * 4);
                __align__(8) unsigned short o[4] = {f2b(v.x), f2b(v.y), f2b(v.z), f2b(v.w)};
                *(uint2*)((char*)As + e * 8) = *(const uint2*)o;
            }
        } else {
            const unsigned short* Ab = (const unsigned short*)Aptr;
#pragma unroll
            for (int i = 0; i < 2; i++) {
                int e = i * 256 + tid;
                int row = e >> 2, seg = e & 3;
                gload_lds16(Ab + (size_t)(m0 + row) * K + kt + seg * 8,
                            (char*)As + e * 16);
            }
        }
        __syncthreads();   // drains vmcnt (global_load_lds) + lgkmcnt

        bf16x8 a[4], b[4];
#pragma unroll
        for (int mt = 0; mt < 4; mt++)
            a[mt] = *(const bf16x8*)(As + (wm + mt * 16 + l16) * BK + quad * 8);
#pragma unroll
        for (int nt = 0; nt < 4; nt++)
            b[nt] = *(const bf16x8*)(Bs + (wn + nt * 16 + l16) * BK + quad * 8);
#pragma unroll
        for (int mt = 0; mt < 4; mt++)
#pragma unroll
            for (int nt = 0; nt < 4; nt++)
                acc[mt][nt] = __builtin_amdgcn_mfma_f32_16x16x32_bf16(
                    a[mt], b[nt], acc[mt][nt], 0, 0, 0);
    }

    // epilogue: C/D layout row=(lane>>4)*4+r, col=lane&15  [m89/m91-verified]
#pragma unroll
    for (int mt = 0; mt < 4; mt++) {
#pragma unroll
        for (int nt = 0; nt < 4; nt++) {
            int n = n0 + wn + nt * 16 + l16;
            float bv = bias[n];
#pragma unroll
            for (int r = 0; r < 4; r++) {
                int m = m0 + wm + mt * 16 + quad * 4 + r;
                C[(size_t)m * N + n] = acc[mt][nt][r] + bv;
            }
        }
    }
}

// ---------- ultra fallback (ws too small): direct fp32 ----------
__global__ __launch_bounds__(256) void naive_wq(
    const float* __restrict__ x, const int* __restrict__ qw,
    const int* __restrict__ qz, const float* __restrict__ sc,
    const float* __restrict__ bias, float* __restrict__ out,
    int M, int N, int K, int gs)
{
    int n = blockIdx.x * 64 + (threadIdx.x & 63);
    int m = blockIdx.y * 4 + (threadIdx.x >> 6);
    if (m >= M || n >= N) return;
    int np8 = N >> 3, sh = (n & 7) * 4;
    float acc = 0.f;
    for (int k = 0; k < K; k++) {
        int g = k / gs;
        int q = (qw[(size_t)k * np8 + (n >> 3)] >> sh) & 15;
        int z = (qz[(size_t)g * np8 + (n >> 3)] >> sh) & 15;
        acc += x[(size_t)m * K + k] * (float)(q - z) * sc[(size_t)g * N + n];
    }
    out[(size_t)m * N + n] = acc + bias[n];
}

// ---------- launch ----------
extern "C" void kernel_launch(void* const* d_in, const int* in_sizes, int n_in,
                              void* d_out, int out_size, void* d_ws, size_t ws_size,
                              hipStream_t stream)
{
    const float* x    = (const float*)d_in[0];
    const int*   qw   = (const int*)d_in[1];
    const int*   qz   = (const int*)d_in[2];
    const float* sc   = (const float*)d_in[3];
    const float* bias = (const float*)d_in[4];
    float* out = (float*)d_out;

    const int N  = in_sizes[4];                 // bias
    const int K  = (int)((size_t)in_sizes[1] * 8 / N);
    const int M  = in_sizes[0] / K;             // B*S
    const int G  = in_sizes[3] / N;
    const int gs = K / G;

    const size_t wt_bytes = (size_t)N * K * 2;
    const size_t xb_bytes = (size_t)M * K * 2;

    if (ws_size < wt_bytes) {
        naive_wq<<<dim3(N / 64, M / 4), 256, 0, stream>>>(x, qw, qz, sc, bias, out, M, N, K, gs);
        return;
    }

    unsigned short* Wt = (unsigned short*)d_ws;
    dequant_wt<<<dim3(K / 64, N / 64), 256, 0, stream>>>(qw, qz, sc, Wt, K, N, gs);

    if (ws_size >= wt_bytes + xb_bytes) {
        unsigned short* xb = (unsigned short*)((char*)d_ws + wt_bytes);
        size_t nx = (size_t)M * K;
        convert_x<<<(unsigned)((nx / 8 + 255) / 256), 256, 0, stream>>>(x, xb, nx);
        gemm_bt<false><<<dim3(N / 128, M / 128), 256, 0, stream>>>(xb, Wt, bias, out, M, N, K);
    } else {
        gemm_bt<true><<<dim3(N / 128, M / 128), 256, 0, stream>>>(x, Wt, bias, out, M, N, K);
    }
}

// Round 2
// 448.764 us; speedup vs baseline: 1.2973x; 1.2973x over previous
//
#include <hip/hip_runtime.h>

// ---------- helpers ----------

__device__ inline unsigned short f2b(float f) {
    union { float f; unsigned u; } v; v.f = f;
    unsigned u = v.u;
    u += 0x7FFFu + ((u >> 16) & 1u);   // RNE
    return (unsigned short)(u >> 16);
}

__device__ inline void gload_lds16(const void* gptr, void* ldsptr) {
    __builtin_amdgcn_global_load_lds(
        (const __attribute__((address_space(1))) unsigned int*)gptr,
        (__attribute__((address_space(3))) unsigned int*)ldsptr,
        16, 0, 0);
}

typedef __attribute__((ext_vector_type(8))) short  bf16x8;
typedef __attribute__((ext_vector_type(4))) float  f32x4;
typedef __attribute__((ext_vector_type(4))) int    i32x4;
typedef __attribute__((ext_vector_type(16))) int   i32x16;

// ================= i8 path =================

// ---- quantize x rows to i8 with per-row scale ----
// one block per row; K multiple of 1024, K<=8192.
__global__ __launch_bounds__(256) void quant_x(
    const float* __restrict__ x, signed char* __restrict__ xq,
    float* __restrict__ sx, int K)
{
    const int row = blockIdx.x, tid = threadIdx.x;
    const float* xr = x + (size_t)row * K;
    const int nseg = K >> 10;
    float4 v[8];
    float mx = 0.f;
#pragma unroll 8
    for (int j = 0; j < nseg; j++) {
        v[j] = *(const float4*)(xr + j * 1024 + tid * 4);
        mx = fmaxf(mx, fmaxf(fmaxf(fabsf(v[j].x), fabsf(v[j].y)),
                             fmaxf(fabsf(v[j].z), fabsf(v[j].w))));
    }
#pragma unroll
    for (int off = 32; off > 0; off >>= 1)
        mx = fmaxf(mx, __shfl_down(mx, off));
    __shared__ float red[4];
    if ((tid & 63) == 0) red[tid >> 6] = mx;
    __syncthreads();
    mx = fmaxf(fmaxf(red[0], red[1]), fmaxf(red[2], red[3]));
    const float inv = mx > 0.f ? 127.f / mx : 0.f;
#pragma unroll 8
    for (int j = 0; j < nseg; j++) {
        int q0 = (int)rintf(v[j].x * inv);
        int q1 = (int)rintf(v[j].y * inv);
        int q2 = (int)rintf(v[j].z * inv);
        int q3 = (int)rintf(v[j].w * inv);
        unsigned u = (q0 & 0xff) | ((q1 & 0xff) << 8) |
                     ((q2 & 0xff) << 16) | ((q3 & 0xff) << 24);
        *(unsigned*)(xq + (size_t)row * K + j * 1024 + tid * 4) = u;
    }
    if (tid == 0) sx[row] = mx > 0.f ? mx / 127.f : 0.f;
}

// ---- unpack qweight - qzeros -> Wq [N][K] i8 (transposed via LDS) ----
__global__ __launch_bounds__(256) void unpack_wq(
    const int* __restrict__ qw, const int* __restrict__ qz,
    signed char* __restrict__ Wq, int K, int N, int gs)
{
    __shared__ int tile[64 * 65];   // [n_local][k_local] as int, 2-way-free banks
    const int k0 = blockIdx.x * 64, n0 = blockIdx.y * 64;
    const int g  = k0 / gs;         // gs % 64 == 0 guaranteed by host
    const int np8 = N >> 3;
    const int tid = threadIdx.x;
    const int zw = qz[(size_t)g * np8 + (n0 >> 3) + (tid & 7)];
#pragma unroll
    for (int i = 0; i < 2; i++) {
        int e  = i * 256 + tid;
        int kk = e >> 3, pp = e & 7;
        int w = qw[(size_t)(k0 + kk) * np8 + (n0 >> 3) + pp];
#pragma unroll
        for (int j = 0; j < 8; j++) {
            int q  = (w >> (4 * j)) & 15;
            int zz = (zw >> (4 * j)) & 15;
            tile[(pp * 8 + j) * 65 + kk] = q - zz;
        }
    }
    __syncthreads();
    // 256 threads: nn = tid>>2 (0..63), kc = tid&3 -> 16 k's each
    const int nn = tid >> 2, kc = tid & 3;
    __align__(16) signed char o[16];
#pragma unroll
    for (int j = 0; j < 16; j++) o[j] = (signed char)tile[nn * 65 + kc * 16 + j];
    *(uint4*)(Wq + (size_t)(n0 + nn) * K + k0 + kc * 16) = *(const uint4*)o;
}

// ---- i8 MFMA GEMM: 128x128 tile, K-tile = 128 (= group), XOR-swizzled LDS ----
__global__ __launch_bounds__(256) void gemm_i8(
    const signed char* __restrict__ Aq, const signed char* __restrict__ Bq,
    const float* __restrict__ sx, const float* __restrict__ sc,
    const float* __restrict__ bias, float* __restrict__ C,
    int M, int N, int K)
{
    __shared__ signed char As[128 * 128];   // 16 KB
    __shared__ signed char Bs[128 * 128];   // 16 KB
    const int tid = threadIdx.x, wave = tid >> 6, lane = tid & 63;
    const int l32 = lane & 31, kh = lane >> 5;
    const int n0 = blockIdx.x * 128, m0 = blockIdx.y * 128;
    const int wm = (wave >> 1) * 64, wn = (wave & 1) * 64;
    const int G = K >> 7;

    float accf[2][2][16] = {};

    for (int g = 0; g < G; g++) {
        __syncthreads();
        // stage A and B tiles: 128 rows x 128 B each; global chunk XOR-swizzled
#pragma unroll
        for (int i = 0; i < 4; i++) {
            int e = i * 256 + tid;
            int row = e >> 3, p = e & 7;
            int cs = ((p ^ (row & 7)) << 4);
            gload_lds16(Aq + (size_t)(m0 + row) * K + g * 128 + cs, As + e * 16);
            gload_lds16(Bq + (size_t)(n0 + row) * K + g * 128 + cs, Bs + e * 16);
        }
        // prefetch this group's scales for our two n-columns
        float s0 = sc[(size_t)g * N + n0 + wn + l32];
        float s1 = sc[(size_t)g * N + n0 + wn + 32 + l32];
        __syncthreads();

        i32x16 acci[2][2] = {};
#pragma unroll
        for (int ks = 0; ks < 4; ks++) {
            const int kc = ks * 2 + kh;     // 16B chunk index, per k-half
            i32x4 a[2], b[2];
#pragma unroll
            for (int mt = 0; mt < 2; mt++) {
                int r = wm + mt * 32 + l32;
                a[mt] = *(const i32x4*)(As + r * 128 + ((kc ^ (r & 7)) << 4));
            }
#pragma unroll
            for (int nt = 0; nt < 2; nt++) {
                int r = wn + nt * 32 + l32;
                b[nt] = *(const i32x4*)(Bs + r * 128 + ((kc ^ (r & 7)) << 4));
            }
#pragma unroll
            for (int mt = 0; mt < 2; mt++)
#pragma unroll
                for (int nt = 0; nt < 2; nt++)
                    acci[mt][nt] = __builtin_amdgcn_mfma_i32_32x32x32_i8(
                        a[mt], b[nt], acci[mt][nt], 0, 0, 0);
        }
        // per-group fp32 fixup: accf += s[g,n] * acc_i32
#pragma unroll
        for (int mt = 0; mt < 2; mt++)
#pragma unroll
            for (int nt = 0; nt < 2; nt++) {
                float s = nt ? s1 : s0;
#pragma unroll
                for (int r = 0; r < 16; r++)
                    accf[mt][nt][r] += s * (float)acci[mt][nt][r];
            }
    }

    // epilogue: C/D 32x32 layout col=lane&31, row=(r&3)+8*(r>>2)+4*kh [m74/m101]
#pragma unroll
    for (int mt = 0; mt < 2; mt++)
#pragma unroll
        for (int nt = 0; nt < 2; nt++) {
            int col = n0 + wn + nt * 32 + l32;
            float bv = bias[col];
#pragma unroll
            for (int r = 0; r < 16; r++) {
                int rowm = m0 + wm + mt * 32 + (r & 3) + 8 * (r >> 2) + 4 * kh;
                C[(size_t)rowm * N + col] = accf[mt][nt][r] * sx[rowm] + bv;
            }
        }
}

// ================= bf16 fallback path (R1, verified) =================

__global__ __launch_bounds__(256) void dequant_wt(
    const int* __restrict__ qw, const int* __restrict__ qz,
    const float* __restrict__ sc, unsigned short* __restrict__ Wt,
    int K, int N, int gs)
{
    __shared__ float tile[64 * 65];
    const int k0 = blockIdx.x * 64, n0 = blockIdx.y * 64;
    const int g  = k0 / gs;
    const int np8 = N >> 3;
    const int tid = threadIdx.x;
#pragma unroll
    for (int i = 0; i < 2; i++) {
        int e  = i * 256 + tid;
        int kk = e >> 3, pp = e & 7;
        int w = qw[(size_t)(k0 + kk) * np8 + (n0 >> 3) + pp];
        int z = qz[(size_t)g * np8 + (n0 >> 3) + pp];
        const float* s = sc + (size_t)g * N + n0 + pp * 8;
#pragma unroll
        for (int j = 0; j < 8; j++) {
            int q  = (w >> (4 * j)) & 15;
            int zz = (z >> (4 * j)) & 15;
            tile[(pp * 8 + j) * 65 + kk] = (float)(q - zz) * s[j];
        }
    }
    __syncthreads();
#pragma unroll
    for (int i = 0; i < 2; i++) {
        int e   = i * 256 + tid;
        int nn  = e >> 3, kk0 = (e & 7) * 8;
        __align__(16) unsigned short o[8];
#pragma unroll
        for (int j = 0; j < 8; j++) o[j] = f2b(tile[nn * 65 + kk0 + j]);
        *(uint4*)(Wt + (size_t)(n0 + nn) * K + k0 + kk0) = *(const uint4*)o;
    }
}

__global__ __launch_bounds__(256) void convert_x(
    const float* __restrict__ x, unsigned short* __restrict__ xb, size_t n)
{
    size_t i = ((size_t)blockIdx.x * 256 + threadIdx.x) * 8;
    if (i >= n) return;
    float4 v0 = *(const float4*)(x + i);
    float4 v1 = *(const float4*)(x + i + 4);
    __align__(16) unsigned short o[8] = {
        f2b(v0.x), f2b(v0.y), f2b(v0.z), f2b(v0.w),
        f2b(v1.x), f2b(v1.y), f2b(v1.z), f2b(v1.w)};
    *(uint4*)(xb + i) = *(const uint4*)o;
}

template <bool A_F32>
__global__ __launch_bounds__(256) void gemm_bt(
    const void* __restrict__ Aptr, const unsigned short* __restrict__ Bt,
    const float* __restrict__ bias, float* __restrict__ C,
    int M, int N, int K)
{
    constexpr int BM = 128, BN = 128, BK = 32;
    __shared__ unsigned short As[BM * BK];
    __shared__ unsigned short Bs[BN * BK];
    const int tid  = threadIdx.x;
    const int wave = tid >> 6, lane = tid & 63;
    const int quad = lane >> 4, l16 = lane & 15;
    const int n0 = blockIdx.x * BN;
    const int m0 = blockIdx.y * BM;
    const int wm = (wave >> 1) * 64, wn = (wave & 1) * 64;
    f32x4 acc[4][4] = {};
    for (int kt = 0; kt < K; kt += BK) {
        __syncthreads();
#pragma unroll
        for (int i = 0; i < 2; i++) {
            int e = i * 256 + tid;
            int row = e >> 2, seg = e & 3;
            gload_lds16(Bt + (size_t)(n0 + row) * K + kt + seg * 8,
                        (char*)Bs + e * 16);
        }
        if (A_F32) {
            const float* Af = (const float*)Aptr;
#pragma unroll
            for (int i = 0; i < 4; i++) {
                int e = i * 256 + tid;
                int row = e >> 3, seg = e & 7;
                float4 v = *(const float4*)(Af + (size_t)(m0 + row) * K + kt + seg * 4);
                __align__(8) unsigned short o[4] = {f2b(v.x), f2b(v.y), f2b(v.z), f2b(v.w)};
                *(uint2*)((char*)As + e * 8) = *(const uint2*)o;
            }
        } else {
            const unsigned short* Ab = (const unsigned short*)Aptr;
#pragma unroll
            for (int i = 0; i < 2; i++) {
                int e = i * 256 + tid;
                int row = e >> 2, seg = e & 3;
                gload_lds16(Ab + (size_t)(m0 + row) * K + kt + seg * 8,
                            (char*)As + e * 16);
            }
        }
        __syncthreads();
        bf16x8 a[4], b[4];
#pragma unroll
        for (int mt = 0; mt < 4; mt++)
            a[mt] = *(const bf16x8*)(As + (wm + mt * 16 + l16) * BK + quad * 8);
#pragma unroll
        for (int nt = 0; nt < 4; nt++)
            b[nt] = *(const bf16x8*)(Bs + (wn + nt * 16 + l16) * BK + quad * 8);
#pragma unroll
        for (int mt = 0; mt < 4; mt++)
#pragma unroll
            for (int nt = 0; nt < 4; nt++)
                acc[mt][nt] = __builtin_amdgcn_mfma_f32_16x16x32_bf16(
                    a[mt], b[nt], acc[mt][nt], 0, 0, 0);
    }
#pragma unroll
    for (int mt = 0; mt < 4; mt++)
#pragma unroll
        for (int nt = 0; nt < 4; nt++) {
            int n = n0 + wn + nt * 16 + l16;
            float bv = bias[n];
#pragma unroll
            for (int r = 0; r < 4; r++) {
                int m = m0 + wm + mt * 16 + quad * 4 + r;
                C[(size_t)m * N + n] = acc[mt][nt][r] + bv;
            }
        }
}

__global__ __launch_bounds__(256) void naive_wq(
    const float* __restrict__ x, const int* __restrict__ qw,
    const int* __restrict__ qz, const float* __restrict__ sc,
    const float* __restrict__ bias, float* __restrict__ out,
    int M, int N, int K, int gs)
{
    int n = blockIdx.x * 64 + (threadIdx.x & 63);
    int m = blockIdx.y * 4 + (threadIdx.x >> 6);
    if (m >= M || n >= N) return;
    int np8 = N >> 3, sh = (n & 7) * 4;
    float acc = 0.f;
    for (int k = 0; k < K; k++) {
        int g = k / gs;
        int q = (qw[(size_t)k * np8 + (n >> 3)] >> sh) & 15;
        int z = (qz[(size_t)g * np8 + (n >> 3)] >> sh) & 15;
        acc += x[(size_t)m * K + k] * (float)(q - z) * sc[(size_t)g * N + n];
    }
    out[(size_t)m * N + n] = acc + bias[n];
}

// ---------- launch ----------
extern "C" void kernel_launch(void* const* d_in, const int* in_sizes, int n_in,
                              void* d_out, int out_size, void* d_ws, size_t ws_size,
                              hipStream_t stream)
{
    const float* x    = (const float*)d_in[0];
    const int*   qw   = (const int*)d_in[1];
    const int*   qz   = (const int*)d_in[2];
    const float* sc   = (const float*)d_in[3];
    const float* bias = (const float*)d_in[4];
    float* out = (float*)d_out;

    const int N  = in_sizes[4];
    const int K  = (int)((size_t)in_sizes[1] * 8 / N);
    const int M  = in_sizes[0] / K;
    const int G  = in_sizes[3] / N;
    const int gs = K / G;

    const size_t xq_b = (size_t)M * K;
    const size_t wq_b = (size_t)N * K;
    const size_t sx_b = (size_t)M * 4;

    const bool i8ok = (gs % 128) == 0 && (K % 1024) == 0 && K <= 8192 &&
                      (M % 128) == 0 && (N % 128) == 0 && (N % 64) == 0 &&
                      ws_size >= xq_b + wq_b + sx_b;

    if (i8ok) {
        signed char* xq = (signed char*)d_ws;
        signed char* wq = xq + xq_b;
        float*       sx = (float*)(wq + wq_b);
        quant_x<<<M, 256, 0, stream>>>(x, xq, sx, K);
        unpack_wq<<<dim3(K / 64, N / 64), 256, 0, stream>>>(qw, qz, wq, K, N, gs);
        gemm_i8<<<dim3(N / 128, M / 128), 256, 0, stream>>>(xq, wq, sx, sc, bias, out, M, N, K);
        return;
    }

    const size_t wt_bytes = (size_t)N * K * 2;
    const size_t xb_bytes = (size_t)M * K * 2;
    if (ws_size < wt_bytes) {
        naive_wq<<<dim3(N / 64, M / 4), 256, 0, stream>>>(x, qw, qz, sc, bias, out, M, N, K, gs);
        return;
    }
    unsigned short* Wt = (unsigned short*)d_ws;
    dequant_wt<<<dim3(K / 64, N / 64), 256, 0, stream>>>(qw, qz, sc, Wt, K, N, gs);
    if (ws_size >= wt_bytes + xb_bytes) {
        unsigned short* xb = (unsigned short*)((char*)d_ws + wt_bytes);
        size_t nx = (size_t)M * K;
        convert_x<<<(unsigned)((nx / 8 + 255) / 256), 256, 0, stream>>>(x, xb, nx);
        gemm_bt<false><<<dim3(N / 128, M / 128), 256, 0, stream>>>(xb, Wt, bias, out, M, N, K);
    } else {
        gemm_bt<true><<<dim3(N / 128, M / 128), 256, 0, stream>>>(x, Wt, bias, out, M, N, K);
    }
}